// Round 1
// baseline (78.390 us; speedup 1.0000x reference)
//
#include <hip/hip_runtime.h>
#include <hip/hip_fp16.h>

#define B_ 4
#define C_ 16
#define H_ 64
#define W_ 64
#define F_ 32

typedef _Float16 hvec2 __attribute__((ext_vector_type(2)));

static __device__ __forceinline__ __half2 pk2(float lo, float hi) {
    auto v = __builtin_amdgcn_cvt_pkrtz(lo, hi);   // single v_cvt_pkrtz_f16_f32
    return __builtin_bit_cast(__half2, v);
}
static __device__ __forceinline__ __half2 bc2(unsigned u) {
    return __builtin_bit_cast(__half2, u);
}

// Single fused kernel: no workspace, no pack prolog.
// Block 512 = 64 cols x 8 channel-pair waves; block covers a 4-row tile of one (b,f).
// x: per-thread own-column f32 loads (6 padded rows x 2 planes) -> cvt_pkrtz ->
//    left/right neighbor half2 via wave shuffles (W=64 == wave width, edges zeroed).
// coeffs: each wave converts its 90 half2 (f,pr) coeffs into LDS once per block
//    (12-slot padded taps -> 48B stride, 16B-aligned ds_read_b128 broadcast reads).
__global__ __launch_bounds__(512)
void ka_fused_kernel(const float* __restrict__ x,
                     const float* __restrict__ nums,
                     const float* __restrict__ denoms,
                     float* __restrict__ out) {
    __shared__ __half2 cLds[8 * 9 * 12];   // 3456 B packed coeffs
    __shared__ float red[8 * 4 * 64];      // 8 KB reduction buffer

    const int tid = threadIdx.x;
    const int col = tid & 63;
    const int wg  = tid >> 6;              // channel-pair 0..7 (wave-uniform)

    int bid = blockIdx.x;
    const int f  = bid & 31;  bid >>= 5;
    const int t4 = bid & 15;
    const int b  = bid >> 4;
    const int gy0 = t4 * 4;

    const int pr = __builtin_amdgcn_readfirstlane(wg);

    // ---- issue x loads early: own column, 6 padded rows, channels pr / pr+8 ----
    const float* xlo = x + ((size_t)(b * C_ + pr))     * (H_ * W_) + col;
    const float* xhi = x + ((size_t)(b * C_ + pr + 8)) * (H_ * W_) + col;
    float vlo[6], vhi[6];
    #pragma unroll
    for (int k = 0; k < 6; ++k) {
        const int r = gy0 + k - 1;                 // block-uniform predicate
        vlo[k] = 0.f; vhi[k] = 0.f;
        if ((unsigned)r < (unsigned)H_) {
            vlo[k] = xlo[r * W_];
            vhi[k] = xhi[r * W_];
        }
    }

    // ---- cooperative coeff conversion: wave wg stages its own (f,pr) block ----
    {
        const int base_lo = (f * C_ + pr) * 9;
        const int base_hi = (f * C_ + pr + 8) * 9;
        #pragma unroll
        for (int e0 = 0; e0 < 128; e0 += 64) {
            const int e = col + e0;                // entries 0..89: (tap, q)
            if (e < 90) {
                const int tap = e / 10;
                const int q   = e - tap * 10;
                float a, c;
                if (q < 6) {
                    a = nums[(size_t)(base_lo + tap) * 6 + q];
                    c = nums[(size_t)(base_hi + tap) * 6 + q];
                } else {
                    a = denoms[(size_t)(base_lo + tap) * 4 + (q - 6)];
                    c = denoms[(size_t)(base_hi + tap) * 4 + (q - 6)];
                }
                cLds[(wg * 9 + tap) * 12 + q] = pk2(a, c);
            }
        }
    }

    // ---- build rv: per padded row, half2 at cols col-1, col, col+1 ----
    uint3 rv[6];
    #pragma unroll
    for (int k = 0; k < 6; ++k) {
        const unsigned u0 = __builtin_bit_cast(unsigned, pk2(vlo[k], vhi[k]));
        unsigned um = (unsigned)__shfl_up((int)u0, 1);
        unsigned up = (unsigned)__shfl_down((int)u0, 1);
        if (col == 0)  um = 0u;                    // left spatial padding
        if (col == 63) up = 0u;                    // right spatial padding
        rv[k].x = um; rv[k].y = u0; rv[k].z = up;
    }

    __syncthreads();                               // coeffs visible

    const __half2 one = __halves2half2(__half(1.0f), __half(1.0f));
    float acc[4] = {0.f, 0.f, 0.f, 0.f};
    const __half2* cb = &cLds[wg * 9 * 12];

    #pragma unroll
    for (int t = 0; t < 9; ++t) {
        const uint4 wA = *(const uint4*)(cb + t * 12);       // n0..n3
        const uint4 wB = *(const uint4*)(cb + t * 12 + 4);   // n4,n5,d0,d1
        const uint2 wC = *(const uint2*)(cb + t * 12 + 8);   // d2,d3
        const __half2 n0 = bc2(wA.x), n1 = bc2(wA.y), n2 = bc2(wA.z), n3 = bc2(wA.w);
        const __half2 n4 = bc2(wB.x), n5 = bc2(wB.y);
        const __half2 d0 = bc2(wB.z), d1 = bc2(wB.w);
        const __half2 d2 = bc2(wC.x), d3 = bc2(wC.y);
        const int a = t / 3, j = t % 3;
        #pragma unroll
        for (int p = 0; p < 4; ++p) {
            const uint3 r3 = rv[p + a];
            const unsigned u = (j == 0) ? r3.x : (j == 1) ? r3.y : r3.z;
            const __half2 xp = bc2(u);

            __half2 P = __hfma2(n5, xp, n4);
            P = __hfma2(P, xp, n3);
            P = __hfma2(P, xp, n2);
            P = __hfma2(P, xp, n1);
            P = __hfma2(P, xp, n0);

            __half2 Sd = __hfma2(d3, xp, d2);
            Sd = __hfma2(Sd, xp, d1);
            Sd = __hfma2(Sd, xp, d0);
            Sd = __hmul2(Sd, xp);

            const __half2 Q = __hadd2(one, __habs2(Sd));
            const __half2 R = h2rcp(Q);
            acc[p] = __builtin_amdgcn_fdot2(__builtin_bit_cast(hvec2, P),
                                            __builtin_bit_cast(hvec2, R),
                                            acc[p], false);
        }
    }

    // ---- reduction across the 8 channel-pair waves ----
    #pragma unroll
    for (int p = 0; p < 4; ++p)
        red[(wg * 4 + p) * 64 + col] = acc[p];
    __syncthreads();
    if (wg < 4) {
        float s = 0.f;
        #pragma unroll
        for (int q = 0; q < 8; ++q)
            s += red[(q * 4 + wg) * 64 + col];
        out[(((size_t)b * F_ + f) * H_ + gy0 + wg) * W_ + col] = s;
    }
}

extern "C" void kernel_launch(void* const* d_in, const int* in_sizes, int n_in,
                              void* d_out, int out_size, void* d_ws, size_t ws_size,
                              hipStream_t stream) {
    const float* x      = (const float*)d_in[0];
    const float* nums   = (const float*)d_in[1];
    const float* denoms = (const float*)d_in[2];
    (void)d_ws; (void)ws_size;   // workspace intentionally untouched
    ka_fused_kernel<<<dim3(B_ * 16 * F_), 512, 0, stream>>>(x, nums, denoms, (float*)d_out);
}

// Round 2
// 78.335 us; speedup vs baseline: 1.0007x; 1.0007x over previous
//
#include <hip/hip_runtime.h>
#include <hip/hip_fp16.h>

#define B_ 4
#define C_ 16
#define H_ 64
#define W_ 64
#define F_ 32
#define PASSES 11   // measurement probe: marginal pass cost = eval-core time

typedef _Float16 hvec2 __attribute__((ext_vector_type(2)));

static __device__ __forceinline__ __half2 pk2(float lo, float hi) {
    auto v = __builtin_amdgcn_cvt_pkrtz(lo, hi);
    return __builtin_bit_cast(__half2, v);
}
static __device__ __forceinline__ __half2 bc2(unsigned u) {
    return __builtin_bit_cast(__half2, u);
}

// PROBE build of the fused kernel: identical math/result, but the 9-tap eval
// core executes PASSES times (outer loop NOT unrolled; rv[] is asm-laundered
// every pass so no pass is loop-invariant -> no LICM/CSE deletion, rule #17).
// Final pass writes the same acc as the 1-pass kernel -> bitwise-same output.
__global__ __launch_bounds__(512)
void ka_fused_kernel(const float* __restrict__ x,
                     const float* __restrict__ nums,
                     const float* __restrict__ denoms,
                     float* __restrict__ out) {
    __shared__ __half2 cLds[8 * 9 * 12];
    __shared__ float red[8 * 4 * 64];

    const int tid = threadIdx.x;
    const int col = tid & 63;
    const int wg  = tid >> 6;

    int bid = blockIdx.x;
    const int f  = bid & 31;  bid >>= 5;
    const int t4 = bid & 15;
    const int b  = bid >> 4;
    const int gy0 = t4 * 4;

    const int pr = __builtin_amdgcn_readfirstlane(wg);

    const float* xlo = x + ((size_t)(b * C_ + pr))     * (H_ * W_) + col;
    const float* xhi = x + ((size_t)(b * C_ + pr + 8)) * (H_ * W_) + col;
    float vlo[6], vhi[6];
    #pragma unroll
    for (int k = 0; k < 6; ++k) {
        const int r = gy0 + k - 1;
        vlo[k] = 0.f; vhi[k] = 0.f;
        if ((unsigned)r < (unsigned)H_) {
            vlo[k] = xlo[r * W_];
            vhi[k] = xhi[r * W_];
        }
    }

    {
        const int base_lo = (f * C_ + pr) * 9;
        const int base_hi = (f * C_ + pr + 8) * 9;
        #pragma unroll
        for (int e0 = 0; e0 < 128; e0 += 64) {
            const int e = col + e0;
            if (e < 90) {
                const int tap = e / 10;
                const int q   = e - tap * 10;
                float a, c;
                if (q < 6) {
                    a = nums[(size_t)(base_lo + tap) * 6 + q];
                    c = nums[(size_t)(base_hi + tap) * 6 + q];
                } else {
                    a = denoms[(size_t)(base_lo + tap) * 4 + (q - 6)];
                    c = denoms[(size_t)(base_hi + tap) * 4 + (q - 6)];
                }
                cLds[(wg * 9 + tap) * 12 + q] = pk2(a, c);
            }
        }
    }

    uint3 rv[6];
    #pragma unroll
    for (int k = 0; k < 6; ++k) {
        const unsigned u0 = __builtin_bit_cast(unsigned, pk2(vlo[k], vhi[k]));
        unsigned um = (unsigned)__shfl_up((int)u0, 1);
        unsigned up = (unsigned)__shfl_down((int)u0, 1);
        if (col == 0)  um = 0u;
        if (col == 63) up = 0u;
        rv[k].x = um; rv[k].y = u0; rv[k].z = up;
    }

    __syncthreads();

    const __half2 one = __halves2half2(__half(1.0f), __half(1.0f));
    const __half2* cb = &cLds[wg * 9 * 12];

    float acc[4];
    #pragma unroll 1
    for (int pass = 0; pass < PASSES; ++pass) {
        // Launder every eval input: opaque redefinition kills loop-invariance.
        #pragma unroll
        for (int k = 0; k < 6; ++k)
            asm volatile("" : "+v"(rv[k].x), "+v"(rv[k].y), "+v"(rv[k].z));

        acc[0] = 0.f; acc[1] = 0.f; acc[2] = 0.f; acc[3] = 0.f;

        #pragma unroll
        for (int t = 0; t < 9; ++t) {
            const uint4 wA = *(const uint4*)(cb + t * 12);
            const uint4 wB = *(const uint4*)(cb + t * 12 + 4);
            const uint2 wC = *(const uint2*)(cb + t * 12 + 8);
            const __half2 n0 = bc2(wA.x), n1 = bc2(wA.y), n2 = bc2(wA.z), n3 = bc2(wA.w);
            const __half2 n4 = bc2(wB.x), n5 = bc2(wB.y);
            const __half2 d0 = bc2(wB.z), d1 = bc2(wB.w);
            const __half2 d2 = bc2(wC.x), d3 = bc2(wC.y);
            const int a = t / 3, j = t % 3;
            #pragma unroll
            for (int p = 0; p < 4; ++p) {
                const uint3 r3 = rv[p + a];
                const unsigned u = (j == 0) ? r3.x : (j == 1) ? r3.y : r3.z;
                const __half2 xp = bc2(u);

                __half2 P = __hfma2(n5, xp, n4);
                P = __hfma2(P, xp, n3);
                P = __hfma2(P, xp, n2);
                P = __hfma2(P, xp, n1);
                P = __hfma2(P, xp, n0);

                __half2 Sd = __hfma2(d3, xp, d2);
                Sd = __hfma2(Sd, xp, d1);
                Sd = __hfma2(Sd, xp, d0);
                Sd = __hmul2(Sd, xp);

                const __half2 Q = __hadd2(one, __habs2(Sd));
                const __half2 R = h2rcp(Q);
                acc[p] = __builtin_amdgcn_fdot2(__builtin_bit_cast(hvec2, P),
                                                __builtin_bit_cast(hvec2, R),
                                                acc[p], false);
            }
        }
    }

    #pragma unroll
    for (int p = 0; p < 4; ++p)
        red[(wg * 4 + p) * 64 + col] = acc[p];
    __syncthreads();
    if (wg < 4) {
        float s = 0.f;
        #pragma unroll
        for (int q = 0; q < 8; ++q)
            s += red[(q * 4 + wg) * 64 + col];
        out[(((size_t)b * F_ + f) * H_ + gy0 + wg) * W_ + col] = s;
    }
}

extern "C" void kernel_launch(void* const* d_in, const int* in_sizes, int n_in,
                              void* d_out, int out_size, void* d_ws, size_t ws_size,
                              hipStream_t stream) {
    const float* x      = (const float*)d_in[0];
    const float* nums   = (const float*)d_in[1];
    const float* denoms = (const float*)d_in[2];
    (void)d_ws; (void)ws_size;
    ka_fused_kernel<<<dim3(B_ * 16 * F_), 512, 0, stream>>>(x, nums, denoms, (float*)d_out);
}